// Round 1
// baseline (393.137 us; speedup 1.0000x reference)
//
#include <hip/hip_runtime.h>
#include <hip/hip_bf16.h>
#include <math.h>

#define BB 2
#define TT 2048
#define CC 2048
#define NH 16
#define NKV 4
#define HD 128
#define BT (BB*TT)
#define WINDOW 1024
#define SQKV 3072   // QKV buffer row stride: Q cols 0-2047, K 2048-2559, V 2560-3071

typedef unsigned short u16;
typedef unsigned int u32;
typedef __attribute__((ext_vector_type(8))) short short8;      // 8 bf16 = 4 VGPRs (MFMA A/B frag)
typedef __attribute__((ext_vector_type(8))) unsigned short ushort8;
typedef __attribute__((ext_vector_type(4))) unsigned short ushort4v;
typedef __attribute__((ext_vector_type(4))) unsigned int u32x4;
typedef __attribute__((ext_vector_type(4))) float floatx4;     // 16x16 MFMA C/D frag
typedef __attribute__((ext_vector_type(16))) float floatx16;   // 32x32 MFMA C/D frag

typedef const __attribute__((address_space(1))) u32* gas_ptr;
typedef __attribute__((address_space(3))) u32* las_ptr;

static __device__ __forceinline__ u16 f2bf(float f) {
    unsigned u = __builtin_bit_cast(unsigned, f);
    return (u16)((u + 0x7fffu + ((u >> 16) & 1u)) >> 16);   // RNE
}
static __device__ __forceinline__ float bf2f(u16 v) {
    unsigned u = ((unsigned)v) << 16;
    return __builtin_bit_cast(float, u);
}

// packed f32x2 -> bf16x2 (RNE), low half = lo, high half = hi
static __device__ __forceinline__ u32 cvt_pk_bf16(float lo, float hi) {
    u32 r;
    asm("v_cvt_pk_bf16_f32 %0, %1, %2" : "=v"(r) : "v"(lo), "v"(hi));
    return r;
}

// softcap+exp: exp(50*tanh(s/50)) = exp2( t*(c0 + c1 t^2 + c2 t^4) ), t=s/50 clamped to [-1,1].
static __device__ __forceinline__ float softcap_exp(float s) {
    float t = s * 0.02f;
    t = fmaxf(-1.0f, fminf(1.0f, t));     // v_med3
    float t2 = t * t;
    float e = t * fmaf(t2, fmaf(t2, 9.617967f, -24.044917f), 72.134752f);
    return __builtin_amdgcn_exp2f(e);
}

// ---------------- elementwise cast fp32 -> bf16 ----------------
__global__ void cast_bf16_kernel(const float* __restrict__ in, u16* __restrict__ out, int n4) {
    int i = blockIdx.x * blockDim.x + threadIdx.x;
    if (i >= n4) return;
    floatx4 v = *(const floatx4*)(in + (size_t)i * 4);
    ushort4v o;
    o[0] = f2bf(v[0]); o[1] = f2bf(v[1]); o[2] = f2bf(v[2]); o[3] = f2bf(v[3]);
    *(ushort4v*)(out + (size_t)i * 4) = o;
}

// ---------------- transpose + cast fp32 [R][Cc] -> bf16 [Cc][R] ----------------
__global__ void transpose_cast_f32_kernel(const float* __restrict__ in, u16* __restrict__ out,
                                          int R, int Cc) {
    __shared__ u16 tile[32][33];
    int c0 = blockIdx.x * 32, r0 = blockIdx.y * 32;
    int tx = threadIdx.x, ty = threadIdx.y;   // block (32, 8)
    #pragma unroll
    for (int i = 0; i < 4; i++) {
        int r = r0 + ty + i * 8;
        tile[ty + i * 8][tx] = f2bf(in[(size_t)r * Cc + c0 + tx]);
    }
    __syncthreads();
    #pragma unroll
    for (int i = 0; i < 4; i++) {
        int c = c0 + ty + i * 8;
        out[(size_t)c * R + r0 + tx] = tile[tx][ty + i * 8];
    }
}

// ---------------- strided transpose bf16: in[r][colOff + c] -> out [Cc][R], batched z ----------------
__global__ void transpose_bf16_kernel(const u16* __restrict__ in, u16* __restrict__ out,
                                      int R, int Cc, int inStride, int colOff,
                                      size_t inBatchStride, size_t outBatchStride) {
    __shared__ u16 tile[32][33];
    int b = blockIdx.z;
    const u16* inb = in + (size_t)b * inBatchStride;
    u16* outb = out + (size_t)b * outBatchStride;
    int c0 = blockIdx.y * 32, r0 = blockIdx.x * 32;
    int tx = threadIdx.x, ty = threadIdx.y;   // block (32, 8)
    #pragma unroll
    for (int i = 0; i < 4; i++) {
        int r = r0 + ty + i * 8;
        tile[ty + i * 8][tx] = inb[(size_t)r * inStride + colOff + c0 + tx];
    }
    __syncthreads();
    #pragma unroll
    for (int i = 0; i < 4; i++) {
        int c = c0 + ty + i * 8;
        outb[(size_t)c * R + r0 + tx] = tile[tx][ty + i * 8];
    }
}

// ---------------- RoPE in-place on rows of `rowStride` elems, H heads x 128, fold scale ----------------
__global__ void rope_kernel(u16* __restrict__ buf, int H, int rowStride, float scale) {
    int idx = blockIdx.x;                 // bt*H + h
    int bt = idx / H, h = idx - bt * H;
    int t = bt % TT;
    int d = threadIdx.x;                  // 0..127
    u16* p = buf + (size_t)bt * rowStride + h * HD;
    float x  = bf2f(p[d]);
    float xp = bf2f(p[d ^ 64]);
    int j = d & 63;
    float inv = exp2f(-0.20762050593046f * (float)j);   // 10000^(-j/64)
    float ang = (float)t * inv;
    float s, c;
    sincosf(ang, &s, &c);
    float rot = (d < 64) ? -xp : xp;
    float o = (x * c + rot * s) * scale;
    __syncthreads();                      // all reads done before any write
    p[d] = f2bf(o);
}

// ---------------- m97-style GEMM: C[M][N] = A[M][K] * Bt[N][K]^T (bf16 in, fp32 acc) ----------------
template <bool OUT_F32>
__global__ __launch_bounds__(256) void gemm128_kernel(const u16* __restrict__ A,
                                                      const u16* __restrict__ Bt,
                                                      void* __restrict__ Cout,
                                                      int M, int N, int K) {
    __shared__ alignas(16) u16 As[128 * 32];   // row-major [128][32], NO padding (lds-dma layout)
    __shared__ alignas(16) u16 Bs[128 * 32];
    int tid = threadIdx.x;
    int w = tid >> 6, lane = tid & 63, quad = lane >> 4, ln = lane & 15;
    int m0 = blockIdx.y * 128;
    int n0 = blockIdx.x * 128;
    int wm = (w >> 1) * 64;
    int wn = (w & 1) * 64;

    int o0 = (w * 2) * 1024 + lane * 16;
    int row0 = o0 >> 6, kc0 = (o0 & 63) >> 4;
    int o1 = o0 + 1024;
    int row1 = o1 >> 6, kc1 = (o1 & 63) >> 4;
    const u16* gA0 = A  + (size_t)(m0 + row0) * K + kc0 * 8;
    const u16* gA1 = A  + (size_t)(m0 + row1) * K + kc1 * 8;
    const u16* gB0 = Bt + (size_t)(n0 + row0) * K + kc0 * 8;
    const u16* gB1 = Bt + (size_t)(n0 + row1) * K + kc1 * 8;
    u16* lA0 = As + (w * 2) * 512;
    u16* lA1 = As + (w * 2 + 1) * 512;
    u16* lB0 = Bs + (w * 2) * 512;
    u16* lB1 = Bs + (w * 2 + 1) * 512;

    floatx4 acc[4][4] = {};

    for (int k0 = 0; k0 < K; k0 += 32) {
        __syncthreads();
        __builtin_amdgcn_global_load_lds((gas_ptr)(gA0 + k0), (las_ptr)lA0, 16, 0, 0);
        __builtin_amdgcn_global_load_lds((gas_ptr)(gA1 + k0), (las_ptr)lA1, 16, 0, 0);
        __builtin_amdgcn_global_load_lds((gas_ptr)(gB0 + k0), (las_ptr)lB0, 16, 0, 0);
        __builtin_amdgcn_global_load_lds((gas_ptr)(gB1 + k0), (las_ptr)lB1, 16, 0, 0);
        __syncthreads();

        short8 af[4], bf[4];
        #pragma unroll
        for (int mt = 0; mt < 4; mt++)
            af[mt] = *(const short8*)(As + (wm + mt * 16 + ln) * 32 + quad * 8);
        #pragma unroll
        for (int nt = 0; nt < 4; nt++)
            bf[nt] = *(const short8*)(Bs + (wn + nt * 16 + ln) * 32 + quad * 8);
        #pragma unroll
        for (int mt = 0; mt < 4; mt++)
            #pragma unroll
            for (int nt = 0; nt < 4; nt++)
                acc[mt][nt] = __builtin_amdgcn_mfma_f32_16x16x32_bf16(af[mt], bf[nt], acc[mt][nt], 0, 0, 0);
    }

    #pragma unroll
    for (int mt = 0; mt < 4; mt++)
      #pragma unroll
      for (int nt = 0; nt < 4; nt++)
        #pragma unroll
        for (int r = 0; r < 4; r++) {
            size_t row = m0 + wm + mt * 16 + quad * 4 + r;
            size_t col = n0 + wn + nt * 16 + ln;
            float v = acc[mt][nt][r];
            if (OUT_F32) ((float*)Cout)[row * N + col] = v;
            else         ((u16*)Cout)[row * N + col] = f2bf(v);
        }
}

// ---------------- flash attention v2: all-register tiles, no LDS in the hot loop ----------------
// Block = 32 queries x (b,h); wave w handles key-tiles j = w, w+4, ...  (fixed-max softmax => additive).
// S^T = mfma(K, Q): lane (q=ln, hi) holds P for its own q column. K A-frag rows are loaded in a
// permuted order sigma so that the S^T output registers are ALREADY in PV B-frag order:
//   sigma(m) = (m&3) + 4*bit3(m) + 8*bit2(m) + 16*bit4(m)
//   => reg r holds key s0 + (r&3) + 4*((r>>2)&1) + 8*hi + 16*(r>>3)
// P->bf16 is then 8 v_cvt_pk, zero cross-lane ops, zero LDS. K double-buffered in regs (prefetch j+4),
// V loaded to regs at tile top (consumed ~600cy later). LDS holds only the cross-wave reduction.
__global__ __launch_bounds__(256, 2) void attn_kernel(const u16* __restrict__ QKV,
                                                      const u16* __restrict__ Vt,
                                                      u16* __restrict__ Enc) {
    // reduction overlay only: red[w] = [32 q][132] fp32 @ w*16896B; Lr[4][32] fp32 @ 67584B
    __shared__ alignas(16) unsigned char pool[68096];

    int tid = threadIdx.x;
    int w = tid >> 6, lane = tid & 63, hi = lane >> 5, ln = lane & 31;
    int hi8 = hi * 8;

    int qb = (63 - (int)blockIdx.x) * 32;       // long blocks first
    int bh = blockIdx.y;
    int b = bh >> 4, h = bh & 15, kh = h >> 2;

    // Q B-frag [n=q=ln][k=hi*8 + ks*16 + j]
    short8 qf[8];
    {
        const u16* qptr = QKV + (size_t)(b * TT + qb + ln) * SQKV + h * HD + hi8;
        #pragma unroll
        for (int ks = 0; ks < 8; ks++) qf[ks] = *(const short8*)(qptr + ks * 16);
    }

    // K row permutation (see header comment)
    int sig = (ln & 3) + (((ln >> 3) & 1) << 2) + (((ln >> 2) & 1) << 3) + ((ln >> 4) << 4);
    const u16* kbase = QKV + (size_t)(b * TT + sig) * SQKV + 2048 + kh * HD + hi8;
    const u16* vbase[4];
    #pragma unroll
    for (int dt = 0; dt < 4; dt++)
        vbase[dt] = Vt + (size_t)((b * NKV + kh) * HD + dt * 32 + ln) * TT + hi8;

    floatx16 O0 = {}, O1 = {}, O2 = {}, O3 = {};   // O^T d-tiles: D[m=d][n=q]
    float lacc = 0.0f;                              // own-half row sum; cross-half folded at end

    int s_lo = qb - WINDOW; if (s_lo < 0) s_lo = 0;
    int ntiles = (qb + 32 - s_lo) >> 5;

    short8 kfA[8], kfB[8];

    auto body = [&](short8 (&kU)[8], short8 (&kP)[8], int j) {
        int s0 = s_lo + j * 32;
        // V frags for this tile (issue early; consumed after softmax)
        short8 vf[4][2];
        #pragma unroll
        for (int dt = 0; dt < 4; dt++) {
            vf[dt][0] = *(const short8*)(vbase[dt] + s0);
            vf[dt][1] = *(const short8*)(vbase[dt] + s0 + 16);
        }
        // K prefetch for this wave's next tile (j+4): full-tile latency cover
        if (j + 4 < ntiles) {
            const u16* kp = kbase + (size_t)(s0 + 128) * SQKV;
            #pragma unroll
            for (int ks = 0; ks < 8; ks++) kP[ks] = *(const short8*)(kp + ks * 16);
        }
        // ---- S^T = K Q^T (rows = sigma-permuted keys, cols = q) ----
        floatx16 S = {};
        #pragma unroll
        for (int ks = 0; ks < 8; ks++)
            S = __builtin_amdgcn_mfma_f32_32x32x16_bf16(kU[ks], qf[ks], S, 0, 0, 0);

        // ---- softcap + exp (+ mask only on the two edge tiles), in place ----
        bool full = (s0 + 31 <= qb) && (s0 >= qb + 31 - WINDOW);
        if (full) {
            #pragma unroll
            for (int r = 0; r < 16; r++) S[r] = softcap_exp(S[r]);
        } else {
            int t = qb + ln;
            #pragma unroll
            for (int r = 0; r < 16; r++) {
                int s = s0 + (r & 3) + (((r >> 2) & 1) << 2) + hi8 + ((r >> 3) << 4);
                bool good = (s <= t) && (s >= t - WINDOW);
                S[r] = good ? softcap_exp(S[r]) : 0.0f;
            }
        }
        // ---- own-half l accumulation (tree) ----
        lacc += ((((S[0] + S[1]) + (S[2] + S[3])) + ((S[4] + S[5]) + (S[6] + S[7])))
               + (((S[8] + S[9]) + (S[10] + S[11])) + ((S[12] + S[13]) + (S[14] + S[15]))));
        // ---- pack P -> bf16 B-frags (already frag-ordered thanks to sigma) ----
        u32x4 w0, w1;
        w0[0] = cvt_pk_bf16(S[0],  S[1]);   w0[1] = cvt_pk_bf16(S[2],  S[3]);
        w0[2] = cvt_pk_bf16(S[4],  S[5]);   w0[3] = cvt_pk_bf16(S[6],  S[7]);
        w1[0] = cvt_pk_bf16(S[8],  S[9]);   w1[1] = cvt_pk_bf16(S[10], S[11]);
        w1[2] = cvt_pk_bf16(S[12], S[13]);  w1[3] = cvt_pk_bf16(S[14], S[15]);
        short8 pf0 = __builtin_bit_cast(short8, w0);
        short8 pf1 = __builtin_bit_cast(short8, w1);
        // ---- O^T += V^T P^T ----
        O0 = __builtin_amdgcn_mfma_f32_32x32x16_bf16(vf[0][0], pf0, O0, 0, 0, 0);
        O0 = __builtin_amdgcn_mfma_f32_32x32x16_bf16(vf[0][1], pf1, O0, 0, 0, 0);
        O1 = __builtin_amdgcn_mfma_f32_32x32x16_bf16(vf[1][0], pf0, O1, 0, 0, 0);
        O1 = __builtin_amdgcn_mfma_f32_32x32x16_bf16(vf[1][1], pf1, O1, 0, 0, 0);
        O2 = __builtin_amdgcn_mfma_f32_32x32x16_bf16(vf[2][0], pf0, O2, 0, 0, 0);
        O2 = __builtin_amdgcn_mfma_f32_32x32x16_bf16(vf[2][1], pf1, O2, 0, 0, 0);
        O3 = __builtin_amdgcn_mfma_f32_32x32x16_bf16(vf[3][0], pf0, O3, 0, 0, 0);
        O3 = __builtin_amdgcn_mfma_f32_32x32x16_bf16(vf[3][1], pf1, O3, 0, 0, 0);
    };

    if (w < ntiles) {
        const u16* k0 = kbase + (size_t)(s_lo + w * 32) * SQKV;
        #pragma unroll
        for (int ks = 0; ks < 8; ks++) kfA[ks] = *(const short8*)(k0 + ks * 16);
        int j = w;
        while (true) {
            body(kfA, kfB, j); j += 4; if (j >= ntiles) break;
            body(kfB, kfA, j); j += 4; if (j >= ntiles) break;
        }
    }
    lacc += __shfl_xor(lacc, 32);                  // fold the other key-half (same q on lane^32)

    // ---- cross-wave reduction of partial (O^T, l): all waves cooperate ----
    float* red = (float*)pool;                 // red[w]: [32 q][132] (pad for banks), 16896 B each
    float* Lr  = (float*)pool + 4 * 4224;      // [4][32]
    {
        float* my = red + w * 4224;
        const floatx16* Os[4] = { &O0, &O1, &O2, &O3 };
        #pragma unroll
        for (int dt = 0; dt < 4; dt++)
            #pragma unroll
            for (int g = 0; g < 4; g++) {
                floatx4 v;
                #pragma unroll
                for (int i = 0; i < 4; i++) v[i] = (*Os[dt])[g * 4 + i];
                // reg r=g*4+i -> d = i + 8g + 4hi (+32dt)
                *(floatx4*)(my + ln * 132 + dt * 32 + g * 8 + hi * 4) = v;
            }
        Lr[w * 32 + ln] = lacc;
    }
    __syncthreads();
    {
        int q = lane >> 1;
        int dbase = w * 32 + (lane & 1) * 16;
        float acc[16] = {};
        #pragma unroll
        for (int pp = 0; pp < 4; pp++) {
            const float* src = red + pp * 4224 + q * 132 + dbase;
            #pragma unroll
            for (int c = 0; c < 4; c++) {
                floatx4 v = *(const floatx4*)(src + c * 4);
                #pragma unroll
                for (int i = 0; i < 4; i++) acc[c * 4 + i] += v[i];
            }
        }
        float lsum = Lr[q] + Lr[32 + q] + Lr[64 + q] + Lr[96 + q];
        float inv = __builtin_amdgcn_rcpf(lsum);
        ushort8 o0, o1;
        #pragma unroll
        for (int i = 0; i < 8; i++) { o0[i] = f2bf(acc[i] * inv); o1[i] = f2bf(acc[8 + i] * inv); }
        u16* dst = Enc + (size_t)(b * TT + qb + q) * (NH * HD) + h * HD + dbase;
        *(ushort8*)(dst) = o0;
        *(ushort8*)(dst + 8) = o1;
    }
}

extern "C" void kernel_launch(void* const* d_in, const int* in_sizes, int n_in,
                              void* d_out, int out_size, void* d_ws, size_t ws_size,
                              hipStream_t stream) {
    const float* x  = (const float*)d_in[0];
    const float* wq = (const float*)d_in[1];
    const float* wk = (const float*)d_in[2];
    const float* wv = (const float*)d_in[3];
    const float* wo = (const float*)d_in[4];
    float* out = (float*)d_out;

    char* ws = (char*)d_ws;
    size_t off = 0;
    auto alloc = [&](size_t bytes) -> void* {
        void* p = ws + off;
        off += (bytes + 255) & ~(size_t)255;
        return p;
    };
    u16* xb    = (u16*)alloc((size_t)BT * CC * 2);
    u16* wqkvT = (u16*)alloc((size_t)SQKV * CC * 2);   // rows: Wq^T 0-2047, Wk^T 2048-2559, Wv^T 2560-3071
    u16* woT   = (u16*)alloc((size_t)CC * CC * 2);
    u16* QKVb  = (u16*)alloc((size_t)BT * SQKV * 2);   // [4096][3072]
    u16* VtT   = (u16*)alloc((size_t)BT * NKV * HD * 2); // [B][NKV][HD][T]
    u16* Enc   = (u16*)alloc((size_t)BT * NH * HD * 2);

    // 1) casts / weight transposes
    cast_bf16_kernel<<<(BT * CC / 4 + 255) / 256, 256, 0, stream>>>(x, xb, BT * CC / 4);
    dim3 tb(32, 8);
    transpose_cast_f32_kernel<<<dim3(CC / 32, CC / 32), tb, 0, stream>>>(wq, wqkvT, CC, CC);
    transpose_cast_f32_kernel<<<dim3(NKV * HD / 32, CC / 32), tb, 0, stream>>>(wk, wqkvT + (size_t)2048 * CC, CC, NKV * HD);
    transpose_cast_f32_kernel<<<dim3(NKV * HD / 32, CC / 32), tb, 0, stream>>>(wv, wqkvT + (size_t)2560 * CC, CC, NKV * HD);
    transpose_cast_f32_kernel<<<dim3(CC / 32, CC / 32), tb, 0, stream>>>(wo, woT, CC, CC);

    // 2) merged QKV projection (N=3072, 768 blocks)
    gemm128_kernel<false><<<dim3(SQKV / 128, BT / 128), 256, 0, stream>>>(xb, wqkvT, QKVb, BT, SQKV, CC);

    // 3) RoPE (scale folded into Q); K at col offset 2048, row stride 3072
    rope_kernel<<<BT * NH, HD, 0, stream>>>(QKVb, NH, SQKV, 0.08838834764831845f);
    rope_kernel<<<BT * NKV, HD, 0, stream>>>(QKVb + 2048, NKV, SQKV, 1.0f);

    // 4) V -> V^T per batch: QKVb cols 2560.. -> [512][T]
    transpose_bf16_kernel<<<dim3(TT / 32, NKV * HD / 32, BB), tb, 0, stream>>>(
        QKVb, VtT, TT, NKV * HD, SQKV, 2560,
        (size_t)TT * SQKV, (size_t)NKV * HD * TT);

    // 5) flash attention: 2048 blocks (64 query-blocks x 32 bh), key-split across waves
    attn_kernel<<<dim3(64, 32), 256, 0, stream>>>(QKVb, VtT, Enc);

    // 6) output projection (fp32 out)
    gemm128_kernel<true><<<dim3(CC / 128, BT / 128), 256, 0, stream>>>(Enc, woT, out, BT, CC, CC);
}

// Round 2
// 329.591 us; speedup vs baseline: 1.1928x; 1.1928x over previous
//
#include <hip/hip_runtime.h>
#include <hip/hip_bf16.h>
#include <math.h>

#define BB 2
#define TT 2048
#define CC 2048
#define NH 16
#define NKV 4
#define HD 128
#define BT (BB*TT)
#define WINDOW 1024
#define SQKV 3072   // QKV buffer row stride: Q cols 0-2047, K 2048-2559, V 2560-3071

typedef unsigned short u16;
typedef unsigned int u32;
typedef __attribute__((ext_vector_type(8))) short short8;      // 8 bf16 = 4 VGPRs (MFMA A/B frag)
typedef __attribute__((ext_vector_type(8))) unsigned short ushort8;
typedef __attribute__((ext_vector_type(4))) unsigned short ushort4v;
typedef __attribute__((ext_vector_type(2))) unsigned int uint2v;
typedef __attribute__((ext_vector_type(4))) float floatx4;     // 16x16 MFMA C/D frag
typedef __attribute__((ext_vector_type(16))) float floatx16;   // 32x32 MFMA C/D frag

typedef const __attribute__((address_space(1))) u32* gas_ptr;
typedef __attribute__((address_space(3))) u32* las_ptr;

static __device__ __forceinline__ u16 f2bf(float f) {
    unsigned u = __builtin_bit_cast(unsigned, f);
    return (u16)((u + 0x7fffu + ((u >> 16) & 1u)) >> 16);   // RNE
}
static __device__ __forceinline__ float bf2f(u16 v) {
    unsigned u = ((unsigned)v) << 16;
    return __builtin_bit_cast(float, u);
}

// packed f32x2 -> bf16x2 (RNE), low half = lo, high half = hi
static __device__ __forceinline__ u32 cvt_pk_bf16(float lo, float hi) {
    u32 r;
    asm("v_cvt_pk_bf16_f32 %0, %1, %2" : "=v"(r) : "v"(lo), "v"(hi));
    return r;
}

// softcap+exp: exp(50*tanh(s/50)) = exp2( t*(c0 + c1 t^2 + c2 t^4) ), t=s/50 clamped to [-1,1].
static __device__ __forceinline__ float softcap_exp(float s) {
    float t = s * 0.02f;
    t = fmaxf(-1.0f, fminf(1.0f, t));     // v_med3
    float t2 = t * t;
    float e = t * fmaf(t2, fmaf(t2, 9.617967f, -24.044917f), 72.134752f);
    return __builtin_amdgcn_exp2f(e);
}

// ---------------- elementwise cast fp32 -> bf16 ----------------
__global__ void cast_bf16_kernel(const float* __restrict__ in, u16* __restrict__ out, int n4) {
    int i = blockIdx.x * blockDim.x + threadIdx.x;
    if (i >= n4) return;
    floatx4 v = *(const floatx4*)(in + (size_t)i * 4);
    ushort4v o;
    o[0] = f2bf(v[0]); o[1] = f2bf(v[1]); o[2] = f2bf(v[2]); o[3] = f2bf(v[3]);
    *(ushort4v*)(out + (size_t)i * 4) = o;
}

// ---------------- transpose + cast fp32 [R][Cc] -> bf16 [Cc][R] ----------------
__global__ void transpose_cast_f32_kernel(const float* __restrict__ in, u16* __restrict__ out,
                                          int R, int Cc) {
    __shared__ u16 tile[32][33];
    int c0 = blockIdx.x * 32, r0 = blockIdx.y * 32;
    int tx = threadIdx.x, ty = threadIdx.y;   // block (32, 8)
    #pragma unroll
    for (int i = 0; i < 4; i++) {
        int r = r0 + ty + i * 8;
        tile[ty + i * 8][tx] = f2bf(in[(size_t)r * Cc + c0 + tx]);
    }
    __syncthreads();
    #pragma unroll
    for (int i = 0; i < 4; i++) {
        int c = c0 + ty + i * 8;
        out[(size_t)c * R + r0 + tx] = tile[tx][ty + i * 8];
    }
}

// ---------------- strided transpose bf16: in[r][colOff + c] -> out [Cc][R], batched z ----------------
__global__ void transpose_bf16_kernel(const u16* __restrict__ in, u16* __restrict__ out,
                                      int R, int Cc, int inStride, int colOff,
                                      size_t inBatchStride, size_t outBatchStride) {
    __shared__ u16 tile[32][33];
    int b = blockIdx.z;
    const u16* inb = in + (size_t)b * inBatchStride;
    u16* outb = out + (size_t)b * outBatchStride;
    int c0 = blockIdx.y * 32, r0 = blockIdx.x * 32;
    int tx = threadIdx.x, ty = threadIdx.y;   // block (32, 8)
    #pragma unroll
    for (int i = 0; i < 4; i++) {
        int r = r0 + ty + i * 8;
        tile[ty + i * 8][tx] = inb[(size_t)r * inStride + colOff + c0 + tx];
    }
    __syncthreads();
    #pragma unroll
    for (int i = 0; i < 4; i++) {
        int c = c0 + ty + i * 8;
        outb[(size_t)c * R + r0 + tx] = tile[tx][ty + i * 8];
    }
}

// ---------------- RoPE in-place on rows of `rowStride` elems, H heads x 128, fold scale ----------------
__global__ void rope_kernel(u16* __restrict__ buf, int H, int rowStride, float scale) {
    int idx = blockIdx.x;                 // bt*H + h
    int bt = idx / H, h = idx - bt * H;
    int t = bt % TT;
    int d = threadIdx.x;                  // 0..127
    u16* p = buf + (size_t)bt * rowStride + h * HD;
    float x  = bf2f(p[d]);
    float xp = bf2f(p[d ^ 64]);
    int j = d & 63;
    float inv = exp2f(-0.20762050593046f * (float)j);   // 10000^(-j/64)
    float ang = (float)t * inv;
    float s, c;
    sincosf(ang, &s, &c);
    float rot = (d < 64) ? -xp : xp;
    float o = (x * c + rot * s) * scale;
    __syncthreads();                      // all reads done before any write
    p[d] = f2bf(o);
}

// ---------------- m97-style GEMM: C[M][N] = A[M][K] * Bt[N][K]^T (bf16 in, fp32 acc) ----------------
template <bool OUT_F32>
__global__ __launch_bounds__(256) void gemm128_kernel(const u16* __restrict__ A,
                                                      const u16* __restrict__ Bt,
                                                      void* __restrict__ Cout,
                                                      int M, int N, int K) {
    __shared__ alignas(16) u16 As[128 * 32];   // row-major [128][32], NO padding (lds-dma layout)
    __shared__ alignas(16) u16 Bs[128 * 32];
    int tid = threadIdx.x;
    int w = tid >> 6, lane = tid & 63, quad = lane >> 4, ln = lane & 15;
    int m0 = blockIdx.y * 128;
    int n0 = blockIdx.x * 128;
    int wm = (w >> 1) * 64;
    int wn = (w & 1) * 64;

    int o0 = (w * 2) * 1024 + lane * 16;
    int row0 = o0 >> 6, kc0 = (o0 & 63) >> 4;
    int o1 = o0 + 1024;
    int row1 = o1 >> 6, kc1 = (o1 & 63) >> 4;
    const u16* gA0 = A  + (size_t)(m0 + row0) * K + kc0 * 8;
    const u16* gA1 = A  + (size_t)(m0 + row1) * K + kc1 * 8;
    const u16* gB0 = Bt + (size_t)(n0 + row0) * K + kc0 * 8;
    const u16* gB1 = Bt + (size_t)(n0 + row1) * K + kc1 * 8;
    u16* lA0 = As + (w * 2) * 512;
    u16* lA1 = As + (w * 2 + 1) * 512;
    u16* lB0 = Bs + (w * 2) * 512;
    u16* lB1 = Bs + (w * 2 + 1) * 512;

    floatx4 acc[4][4] = {};

    for (int k0 = 0; k0 < K; k0 += 32) {
        __syncthreads();
        __builtin_amdgcn_global_load_lds((gas_ptr)(gA0 + k0), (las_ptr)lA0, 16, 0, 0);
        __builtin_amdgcn_global_load_lds((gas_ptr)(gA1 + k0), (las_ptr)lA1, 16, 0, 0);
        __builtin_amdgcn_global_load_lds((gas_ptr)(gB0 + k0), (las_ptr)lB0, 16, 0, 0);
        __builtin_amdgcn_global_load_lds((gas_ptr)(gB1 + k0), (las_ptr)lB1, 16, 0, 0);
        __syncthreads();

        short8 af[4], bf[4];
        #pragma unroll
        for (int mt = 0; mt < 4; mt++)
            af[mt] = *(const short8*)(As + (wm + mt * 16 + ln) * 32 + quad * 8);
        #pragma unroll
        for (int nt = 0; nt < 4; nt++)
            bf[nt] = *(const short8*)(Bs + (wn + nt * 16 + ln) * 32 + quad * 8);
        #pragma unroll
        for (int mt = 0; mt < 4; mt++)
            #pragma unroll
            for (int nt = 0; nt < 4; nt++)
                acc[mt][nt] = __builtin_amdgcn_mfma_f32_16x16x32_bf16(af[mt], bf[nt], acc[mt][nt], 0, 0, 0);
    }

    #pragma unroll
    for (int mt = 0; mt < 4; mt++)
      #pragma unroll
      for (int nt = 0; nt < 4; nt++)
        #pragma unroll
        for (int r = 0; r < 4; r++) {
            size_t row = m0 + wm + mt * 16 + quad * 4 + r;
            size_t col = n0 + wn + nt * 16 + ln;
            float v = acc[mt][nt][r];
            if (OUT_F32) ((float*)Cout)[row * N + col] = v;
            else         ((u16*)Cout)[row * N + col] = f2bf(v);
        }
}

// ---------------- flash attention v3: shared K/V tiles, 128-query blocks ----------------
// Block = 128 queries x (b,h), 4 waves each owning 32 queries. All waves iterate the SAME key
// tiles; K/V staged in LDS once per block via global_load_lds (16 x 1KB DMA, 4 per wave),
// double-buffered with one-tile-ahead prefetch. Raw s_barrier + counted vmcnt(4) (NOT
// __syncthreads -- that drains vmcnt(0) and kills the pipeline).
// LDS layout = read order: every ds_read_b128 is lane-linear over a contiguous 1KB group =>
// conflict-free. Achieved by pre-permuting the per-lane GLOBAL source address of each DMA.
// In-register softmax machinery (sigma-permuted K rows, cvt_pk P-pack) identical to v2:
//   sigma(m) = (m&3) + 4*bit3(m) + 8*bit2(m) + 16*bit4(m)
//   S^T reg r holds key s0 + (r&3) + 4*((r>>2)&1) + 8*hi + 16*(r>>3), col q = ln.
// No cross-wave reduction: each wave owns its 32 queries end-to-end.
__global__ __launch_bounds__(256, 2) void attn_kernel(const u16* __restrict__ QKV,
                                                      const u16* __restrict__ Vt,
                                                      u16* __restrict__ Enc) {
    // buf[2] x { K: 8KB (groups ks=0..7, 1KB each) | V: 8KB (groups g=dt*2+half) } = 32KB
    __shared__ alignas(16) u16 pool[2 * 8192];

    int tid = threadIdx.x;
    int w = tid >> 6, lane = tid & 63, hi = lane >> 5, ln = lane & 31;
    int hi8 = hi * 8;

    int qb = (15 - (int)blockIdx.x) * 128;      // long blocks first
    int bh = blockIdx.y;
    int b = bh >> 4, h = bh & 15, kh = h >> 2;
    int qw = qb + w * 32;                        // this wave's query base

    // Q B-frag [n=q=ln][k=hi*8 + ks*16 + j]
    short8 qf[8];
    {
        const u16* qptr = QKV + (size_t)(b * TT + qw + ln) * SQKV + h * HD + hi8;
        #pragma unroll
        for (int ks = 0; ks < 8; ks++) qf[ks] = *(const short8*)(qptr + ks * 16);
    }

    // ---- DMA source setup: wave w issues groups [w*4, w*4+4) of {K0..7, V0..7} ----
    int sig = (ln & 3) + (((ln >> 3) & 1) << 2) + (((ln >> 2) & 1) << 3) + ((ln >> 4) << 4);
    bool isK = (w < 2);
    const u16* dsrc[4];
    int ldst[4];                                 // u16 offset within a 16KB buffer
    #pragma unroll
    for (int i = 0; i < 4; i++) {
        if (isK) {
            int ks = w * 4 + i;
            // LDS slot (ks, lane l) <- K row s0+sigma(l&31), d-cols (l>>5)*8 + ks*16
            dsrc[i] = QKV + (size_t)(b * TT + sig) * SQKV + 2048 + kh * HD + ks * 16 + hi8;
            ldst[i] = ks * 512;
        } else {
            int g = (w - 2) * 4 + i;
            // LDS slot (g, lane l) <- V^T row (g>>1)*32 + (l&31), keys s0 + (g&1)*16 + (l>>5)*8
            dsrc[i] = Vt + (size_t)((b * NKV + kh) * HD + (g >> 1) * 32 + ln) * TT + (g & 1) * 16 + hi8;
            ldst[i] = 4096 + g * 512;
        }
    }
    size_t addmul = isK ? (size_t)SQKV : (size_t)1;

    floatx16 O0 = {}, O1 = {}, O2 = {}, O3 = {};   // O^T d-tiles: D[m=d][n=q]
    float lacc = 0.0f;

    int S_LO = qb - WINDOW; if (S_LO < 0) S_LO = 0;
    int nt = (qb + 128 - S_LO) >> 5;

    auto issue = [&](int t) {
        int s0 = S_LO + t * 32;
        u16* base = pool + (t & 1) * 8192;
        size_t add = (size_t)s0 * addmul;
        #pragma unroll
        for (int i = 0; i < 4; i++)
            __builtin_amdgcn_global_load_lds((gas_ptr)(dsrc[i] + add), (las_ptr)(base + ldst[i]), 16, 0, 0);
    };

    issue(0);
    for (int t = 0; t < nt; ++t) {
        // barrier A: all waves done reading buf[(t+1)&1] (= tile t-1's buffer)
        __builtin_amdgcn_sched_barrier(0);
        __builtin_amdgcn_s_barrier();
        __builtin_amdgcn_sched_barrier(0);
        if (t + 1 < nt) {
            issue(t + 1);
            __builtin_amdgcn_sched_barrier(0);
            __builtin_amdgcn_s_waitcnt(0x0F74);   // vmcnt(4): own tile-t DMAs landed, t+1 in flight
        } else {
            __builtin_amdgcn_s_waitcnt(0x0F70);   // vmcnt(0): last tile, drain all
        }
        __builtin_amdgcn_sched_barrier(0);
        __builtin_amdgcn_s_barrier();             // barrier B: ALL waves' tile-t data in LDS
        __builtin_amdgcn_sched_barrier(0);

        int s0 = S_LO + t * 32;
        if (s0 > qw + 31 || s0 + 31 < qw - WINDOW) continue;   // tile outside this wave's window

        const u16* Kb = pool + (t & 1) * 8192;
        const u16* Vb = Kb + 4096;

        // ---- S^T = K Q^T (rows = sigma-permuted keys, cols = q) ----
        floatx16 S = {};
        #pragma unroll
        for (int ks = 0; ks < 8; ks++) {
            short8 kf = *(const short8*)(Kb + ks * 512 + lane * 8);   // lane-linear 1KB: conflict-free
            S = __builtin_amdgcn_mfma_f32_32x32x16_bf16(kf, qf[ks], S, 0, 0, 0);
        }

        // ---- softcap + exp (+ mask only on edge tiles), in place ----
        bool full = (s0 + 31 <= qw) && (s0 >= qw + 31 - WINDOW);
        if (full) {
            #pragma unroll
            for (int r = 0; r < 16; r++) S[r] = softcap_exp(S[r]);
        } else {
            int tq = qw + ln;
            #pragma unroll
            for (int r = 0; r < 16; r++) {
                int s = s0 + (r & 3) + (((r >> 2) & 1) << 2) + hi8 + ((r >> 3) << 4);
                bool good = (s <= tq) && (s >= tq - WINDOW);
                S[r] = good ? softcap_exp(S[r]) : 0.0f;
            }
        }

        // ---- own-half l accumulation (tree) ----
        lacc += ((((S[0] + S[1]) + (S[2] + S[3])) + ((S[4] + S[5]) + (S[6] + S[7])))
               + (((S[8] + S[9]) + (S[10] + S[11])) + ((S[12] + S[13]) + (S[14] + S[15]))));

        // ---- pack P -> bf16 B-frags (already frag-ordered thanks to sigma) ----
        u32 w0a = cvt_pk_bf16(S[0],  S[1]),  w0b = cvt_pk_bf16(S[2],  S[3]);
        u32 w0c = cvt_pk_bf16(S[4],  S[5]),  w0d = cvt_pk_bf16(S[6],  S[7]);
        u32 w1a = cvt_pk_bf16(S[8],  S[9]),  w1b = cvt_pk_bf16(S[10], S[11]);
        u32 w1c = cvt_pk_bf16(S[12], S[13]), w1d = cvt_pk_bf16(S[14], S[15]);
        typedef __attribute__((ext_vector_type(4))) unsigned int u32x4t;
        u32x4t pw0 = { w0a, w0b, w0c, w0d };
        u32x4t pw1 = { w1a, w1b, w1c, w1d };
        short8 pf0 = __builtin_bit_cast(short8, pw0);
        short8 pf1 = __builtin_bit_cast(short8, pw1);

        // ---- O^T += V^T P^T (V frags lane-linear 1KB reads: conflict-free) ----
        #pragma unroll
        for (int dt = 0; dt < 4; dt++) {
            short8 vf0 = *(const short8*)(Vb + (dt * 2 + 0) * 512 + lane * 8);
            short8 vf1 = *(const short8*)(Vb + (dt * 2 + 1) * 512 + lane * 8);
            floatx16* Od = (dt == 0) ? &O0 : (dt == 1) ? &O1 : (dt == 2) ? &O2 : &O3;
            *Od = __builtin_amdgcn_mfma_f32_32x32x16_bf16(vf0, pf0, *Od, 0, 0, 0);
            *Od = __builtin_amdgcn_mfma_f32_32x32x16_bf16(vf1, pf1, *Od, 0, 0, 0);
        }
    }

    __syncthreads();   // drain everything; staging LDS is now free for the epilogue

    // ---- epilogue: normalize, transpose O^T -> O via wave-private 2KB LDS bounce ----
    lacc += __shfl_xor(lacc, 32);                  // fold the other key-half (same q on lane^32)
    float inv = __builtin_amdgcn_rcpf(lacc);
    u16* ep = pool + w * 1024;                     // [32 q][32 d] bf16 per dt pass
    const floatx16* Os[4] = { &O0, &O1, &O2, &O3 };
    #pragma unroll
    for (int dt = 0; dt < 4; dt++) {
        #pragma unroll
        for (int g = 0; g < 4; g++) {
            // reg r=g*4+i -> d_local = i + 8g + 4hi, col q=ln
            float a0 = (*Os[dt])[g * 4 + 0] * inv, a1 = (*Os[dt])[g * 4 + 1] * inv;
            float a2 = (*Os[dt])[g * 4 + 2] * inv, a3 = (*Os[dt])[g * 4 + 3] * inv;
            uint2v pk;
            pk[0] = cvt_pk_bf16(a0, a1);
            pk[1] = cvt_pk_bf16(a2, a3);
            *(uint2v*)(ep + ln * 32 + g * 8 + hi * 4) = pk;   // same-wave DS pipe is in-order
        }
        ushort8 r0 = *(const ushort8*)(ep + ln * 32 + hi * 16);
        ushort8 r1 = *(const ushort8*)(ep + ln * 32 + hi * 16 + 8);
        u16* dst = Enc + (size_t)(b * TT + qw + ln) * (NH * HD) + h * HD + dt * 32 + hi * 16;
        *(ushort8*)dst = r0;
        *(ushort8*)(dst + 8) = r1;
    }
}

extern "C" void kernel_launch(void* const* d_in, const int* in_sizes, int n_in,
                              void* d_out, int out_size, void* d_ws, size_t ws_size,
                              hipStream_t stream) {
    const float* x  = (const float*)d_in[0];
    const float* wq = (const float*)d_in[1];
    const float* wk = (const float*)d_in[2];
    const float* wv = (const float*)d_in[3];
    const float* wo = (const float*)d_in[4];
    float* out = (float*)d_out;

    char* ws = (char*)d_ws;
    size_t off = 0;
    auto alloc = [&](size_t bytes) -> void* {
        void* p = ws + off;
        off += (bytes + 255) & ~(size_t)255;
        return p;
    };
    u16* xb    = (u16*)alloc((size_t)BT * CC * 2);
    u16* wqkvT = (u16*)alloc((size_t)SQKV * CC * 2);   // rows: Wq^T 0-2047, Wk^T 2048-2559, Wv^T 2560-3071
    u16* woT   = (u16*)alloc((size_t)CC * CC * 2);
    u16* QKVb  = (u16*)alloc((size_t)BT * SQKV * 2);   // [4096][3072]
    u16* VtT   = (u16*)alloc((size_t)BT * NKV * HD * 2); // [B][NKV][HD][T]
    u16* Enc   = (u16*)alloc((size_t)BT * NH * HD * 2);

    // 1) casts / weight transposes
    cast_bf16_kernel<<<(BT * CC / 4 + 255) / 256, 256, 0, stream>>>(x, xb, BT * CC / 4);
    dim3 tb(32, 8);
    transpose_cast_f32_kernel<<<dim3(CC / 32, CC / 32), tb, 0, stream>>>(wq, wqkvT, CC, CC);
    transpose_cast_f32_kernel<<<dim3(NKV * HD / 32, CC / 32), tb, 0, stream>>>(wk, wqkvT + (size_t)2048 * CC, CC, NKV * HD);
    transpose_cast_f32_kernel<<<dim3(NKV * HD / 32, CC / 32), tb, 0, stream>>>(wv, wqkvT + (size_t)2560 * CC, CC, NKV * HD);
    transpose_cast_f32_kernel<<<dim3(CC / 32, CC / 32), tb, 0, stream>>>(wo, woT, CC, CC);

    // 2) merged QKV projection (N=3072, 768 blocks)
    gemm128_kernel<false><<<dim3(SQKV / 128, BT / 128), 256, 0, stream>>>(xb, wqkvT, QKVb, BT, SQKV, CC);

    // 3) RoPE (scale folded into Q); K at col offset 2048, row stride 3072
    rope_kernel<<<BT * NH, HD, 0, stream>>>(QKVb, NH, SQKV, 0.08838834764831845f);
    rope_kernel<<<BT * NKV, HD, 0, stream>>>(QKVb + 2048, NKV, SQKV, 1.0f);

    // 4) V -> V^T per batch: QKVb cols 2560.. -> [512][T]
    transpose_bf16_kernel<<<dim3(TT / 32, NKV * HD / 32, BB), tb, 0, stream>>>(
        QKVb, VtT, TT, NKV * HD, SQKV, 2560,
        (size_t)TT * SQKV, (size_t)NKV * HD * TT);

    // 5) flash attention: 512 blocks (16 query-blocks x 32 bh), shared K/V tiles per block
    attn_kernel<<<dim3(16, 32), 256, 0, stream>>>(QKVb, VtT, Enc);

    // 6) output projection (fp32 out)
    gemm128_kernel<true><<<dim3(CC / 128, BT / 128), 256, 0, stream>>>(Enc, woT, out, BT, CC, CC);
}